// Round 3
// baseline (797.038 us; speedup 1.0000x reference)
//
#include <hip/hip_runtime.h>
#include <math.h>

// Problem constants
#define B_ 32
#define T_ 4096
#define QD_ 1024
#define MD_ 512
#define AD_ 128
#define F_ 32
#define K_ 31
#define PAD_ 15

#define TT 32                 // timesteps per score block (1 wave per block)
#define NBLK (T_ / TT)        // 128 t-blocks per batch

typedef float f32x16 __attribute__((ext_vector_type(16)));
typedef unsigned int uint4v __attribute__((ext_vector_type(4)));

// round-half-up float->bf16 pair packed in one VGPR via v_perm
__device__ inline unsigned pk_bf2(float lo, float hi) {
    unsigned ul = __float_as_uint(lo) + 0x8000u;
    unsigned uh = __float_as_uint(hi) + 0x8000u;
    return __builtin_amdgcn_perm(uh, ul, 0x07060302u);
}

__device__ inline unsigned short f2bf_rn(float f) {
    unsigned u = __float_as_uint(f);
    u += 0x7fffu + ((u >> 16) & 1u);
    return (unsigned short)(u >> 16);
}

__device__ inline float bf2f(unsigned short u) {
    return __uint_as_float(((unsigned)u) << 16);
}

// v_mfma via inline asm. s_nop 1 covers VALU-write -> MFMA-read hazard.
__device__ inline void mfma32(f32x16& c, uint4v a, uint4v b) {
    asm("s_nop 1\n\tv_mfma_f32_32x32x16_bf16 %0, %1, %2, %0"
        : "+v"(c) : "v"(a), "v"(b));
}

// ---------------- Kernel A: Wm swizzle + pq partials + counter zero ---------
__global__ __launch_bounds__(256) void k_pre(
    const float* __restrict__ Wm, unsigned short* __restrict__ wmT_sw,
    const float* __restrict__ query, const float* __restrict__ Wq,
    float* __restrict__ pqp, int* __restrict__ cnt) {
    __shared__ float s_t[128];
    const int bx = blockIdx.x;
    const int tid = threadIdx.x;
    if (bx < 32) {
        int gid = bx * 256 + tid;   // 0..8191
        int kk = gid >> 8;
        int ct = (gid >> 6) & 3;
        int lane = gid & 63;
        int k0 = kk * 16 + (lane >> 5) * 8;
        int a = ct * 32 + (lane & 31);
        unsigned short o[8];
#pragma unroll
        for (int j = 0; j < 8; j++) o[j] = f2bf_rn(Wm[(k0 + j) * AD_ + a]);
        uint4v v;
        v[0] = ((unsigned)o[1] << 16) | o[0];
        v[1] = ((unsigned)o[3] << 16) | o[2];
        v[2] = ((unsigned)o[5] << 16) | o[4];
        v[3] = ((unsigned)o[7] << 16) | o[6];
        *(uint4v*)(wmT_sw + (long)gid * 8) = v;
        if (bx == 0 && tid < B_) cnt[tid] = 0;
        return;
    }
    // pq partial
    const int pb = bx - 32;            // 0..255
    const int b = pb >> 3, qc = pb & 7;
    const int a = tid & 127, hf = tid >> 7;
    const float* qrow = query + b * QD_ + qc * 128 + hf * 64;
    const float* wq = Wq + (qc * 128 + hf * 64) * AD_ + a;
    float acc = 0.f;
#pragma unroll 4
    for (int i = 0; i < 64; i++) acc += qrow[i] * wq[i * AD_];
    if (hf) s_t[a] = acc;
    __syncthreads();
    if (!hf) pqp[((long)qc * B_ + b) * AD_ + a] = acc + s_t[a];
}

// ---------------- Kernel B: conv + loc@Wl + all biases -> ploc (bf16) -------
__global__ __launch_bounds__(256) void k_ploc(
    const float* __restrict__ alignments, const float* __restrict__ convw,
    const float* __restrict__ convb, const float* __restrict__ Wl,
    const float* __restrict__ bl, const float* __restrict__ bm,
    const float* __restrict__ bq, const float* __restrict__ pqp,
    unsigned short* __restrict__ ploc) {
    __shared__ float s_cw[F_ * 2 * K_];
    __shared__ float s_al[(128 + K_ - 1) * 2];
    __shared__ float s_loc[128 * F_];

    const int tid = threadIdx.x;
    const int b = blockIdx.y;
    const int t0 = blockIdx.x * 128;

    for (int i = tid; i < F_ * 2 * K_; i += 256) s_cw[i] = convw[i];
    for (int i = tid; i < (128 + K_ - 1) * 2; i += 256) {
        int tg = t0 + (i >> 1) - PAD_;
        s_al[i] = (tg >= 0 && tg < T_) ? alignments[((long)b * T_ + tg) * 2 + (i & 1)] : 0.f;
    }
    __syncthreads();

    for (int i = tid; i < 128 * F_; i += 256) {
        int f = i & (F_ - 1);
        int t = i >> 5;
        float acc = convb[f];
        const float* w0 = &s_cw[f * (2 * K_)];
        const float* w1 = w0 + K_;
        const float2* ap = (const float2*)&s_al[t * 2];
#pragma unroll
        for (int k = 0; k < K_; k++) {
            float2 a2 = ap[k];
            acc += a2.x * w0[k] + a2.y * w1[k];
        }
        s_loc[t * F_ + f] = acc;
    }
    __syncthreads();

    const int a = tid & 127;
    float wl[F_];
#pragma unroll
    for (int f = 0; f < F_; f++) wl[f] = Wl[f * AD_ + a];
    float pqv = 0.f;
#pragma unroll
    for (int q = 0; q < 8; q++) pqv += pqp[((long)q * B_ + b) * AD_ + a];
    const float base = pqv + bq[a] + bm[a] + bl[a];
    unsigned short* outp = ploc + ((long)b * T_ + t0) * AD_ + a;
    for (int t = (tid >> 7); t < 128; t += 2) {
        float acc = base;
        const float* lr = &s_loc[t * F_];
#pragma unroll
        for (int f = 0; f < F_; f++) acc += lr[f] * wl[f];
        outp[(long)t * AD_] = f2bf_rn(acc);
    }
}

// ---------------- Kernel C: pipelined 1-wave MFMA score + context + finalize
// One wave per block: M=32 rows (t), N=128 cols (a), K=512 in 16 chunks of 32.
// Depth-1 software pipeline: chunk c+1's 12 loads (A: HBM, B: L2) issue before
// chunk c's pack+MFMA consumes its registers. __launch_bounds__(64,2) raises
// the VGPR budget to 256 so all pipeline registers stay live (R1 was issue-
// serialized at VGPR_Count=48). No barriers in the main loop.
__global__ __launch_bounds__(64, 2) void k_score_ctx(
    const float* __restrict__ memory, const unsigned char* __restrict__ mask,
    const unsigned short* __restrict__ wmT_sw, const unsigned short* __restrict__ ploc,
    const float* __restrict__ vw, const float* __restrict__ vb,
    float* __restrict__ bmax, float* __restrict__ bden,
    float* __restrict__ num, float* __restrict__ oalign,
    float* __restrict__ ctx, int* __restrict__ cnt) {
    __shared__ __align__(16) float s_sc[TT];
    __shared__ __align__(16) float s_w[TT];
    __shared__ float f_m[NBLK], f_f[NBLK];
    __shared__ float f_Ds;
    __shared__ int s_last;

    const int lane = threadIdx.x;
    const int l31 = lane & 31;
    const int h = lane >> 5;
    const int b = blockIdx.y;
    const int blk = blockIdx.x;
    const int t0 = blk * TT;

    const float* aptr = memory + ((long)b * T_ + t0) * MD_;
    const float* arow = aptr + l31 * MD_ + h * 8;     // this lane's fragment source
    const unsigned short* bpk = wmT_sw + lane * 8;

    f32x16 c0, c1, c2, c3;
#pragma unroll
    for (int i = 0; i < 16; i++) { c0[i] = 0.f; c1[i] = 0.f; c2[i] = 0.f; c3[i] = 0.f; }

    // pipeline registers
    float4 A[4], N[4];
    uint4v Bq[8], Mq[8];

    // prologue: chunk 0
#pragma unroll
    for (int j = 0; j < 4; j++)
        A[j] = *(const float4*)(arow + (j & 1) * 4 + (j >> 1) * 16);
#pragma unroll
    for (int j = 0; j < 8; j++)
        Bq[j] = *(const uint4v*)(bpk + j * 512);

#pragma unroll
    for (int c = 0; c < 16; ++c) {
        // issue chunk c+1 loads (independent of everything below)
        if (c < 15) {
            const float* ap = arow + (c + 1) * 32;
#pragma unroll
            for (int j = 0; j < 4; j++)
                N[j] = *(const float4*)(ap + (j & 1) * 4 + (j >> 1) * 16);
            const unsigned short* bc = bpk + ((c + 1) << 12);
#pragma unroll
            for (int j = 0; j < 8; j++)
                Mq[j] = *(const uint4v*)(bc + j * 512);
        }
        // compute chunk c
        uint4v af0, af1;
        af0[0] = pk_bf2(A[0].x, A[0].y); af0[1] = pk_bf2(A[0].z, A[0].w);
        af0[2] = pk_bf2(A[1].x, A[1].y); af0[3] = pk_bf2(A[1].z, A[1].w);
        af1[0] = pk_bf2(A[2].x, A[2].y); af1[1] = pk_bf2(A[2].z, A[2].w);
        af1[2] = pk_bf2(A[3].x, A[3].y); af1[3] = pk_bf2(A[3].z, A[3].w);
        mfma32(c0, af0, Bq[0]); mfma32(c1, af0, Bq[1]);
        mfma32(c2, af0, Bq[2]); mfma32(c3, af0, Bq[3]);
        mfma32(c0, af1, Bq[4]); mfma32(c1, af1, Bq[5]);
        mfma32(c2, af1, Bq[6]); mfma32(c3, af1, Bq[7]);
        // rotate (renamed away by full unroll)
        if (c < 15) {
#pragma unroll
            for (int j = 0; j < 4; j++) A[j] = N[j];
#pragma unroll
            for (int j = 0; j < 8; j++) Bq[j] = Mq[j];
        }
    }
    // drain MFMA->VALU hazard
    asm volatile("s_nop 7\n\ts_nop 7\n\ts_nop 7" ::: "memory");

    // --- epilogue: tanh, dot with v, reduce over a ---
    const unsigned short* plp = ploc + ((long)b * T_ + t0) * AD_ + l31;
    const float vw0 = vw[l31];
    const float vw1 = vw[32 + l31];
    const float vw2 = vw[64 + l31];
    const float vw3 = vw[96 + l31];
#pragma unroll
    for (int i = 0; i < 16; i++) {
        const int row = (i & 3) + 8 * (i >> 2) + 4 * h;
        const unsigned short* pr = plp + row * AD_;
        float s = tanhf(c0[i] + bf2f(pr[0]))  * vw0
                + tanhf(c1[i] + bf2f(pr[32])) * vw1
                + tanhf(c2[i] + bf2f(pr[64])) * vw2
                + tanhf(c3[i] + bf2f(pr[96])) * vw3;
        s += __shfl_xor(s, 1);
        s += __shfl_xor(s, 2);
        s += __shfl_xor(s, 4);
        s += __shfl_xor(s, 8);
        s += __shfl_xor(s, 16);
        if (l31 == 0) s_sc[row] = s;   // two halves cover disjoint rows
    }

    // add v_b, apply mask (lanes 0..31 own one row each)
    if (lane < TT) {
        float s = s_sc[lane] + vb[0];
        if (mask[(long)b * T_ + t0 + lane]) s = -INFINITY;
        s_sc[lane] = s;
    }
    // local softmax stats
    float m = -INFINITY;
#pragma unroll
    for (int r = 0; r < TT; r++) m = fmaxf(m, s_sc[r]);
    float e = 0.f;
    if (lane < TT) {
        e = (m == -INFINITY) ? 0.f : expf(s_sc[lane] - m);
        s_w[lane] = e;
        oalign[(long)b * T_ + t0 + lane] = e;   // rescaled in finalize
    }
    float d = e;
    d += __shfl_xor(d, 1);
    d += __shfl_xor(d, 2);
    d += __shfl_xor(d, 4);
    d += __shfl_xor(d, 8);
    d += __shfl_xor(d, 16);
    if (lane == 0) { bmax[b * NBLK + blk] = m; bden[b * NBLK + blk] = d; }

    // --- partial context: num[md] = sum_t e_t * mem[t][md] (tile L2-hot) ---
    const float2* mp = (const float2*)aptr + lane;
    float2 a0 = make_float2(0.f, 0.f), a1 = make_float2(0.f, 0.f);
    float2 a2 = make_float2(0.f, 0.f), a3 = make_float2(0.f, 0.f);
#pragma unroll 8
    for (int t = 0; t < TT; t++) {
        const float wt = s_w[t];
        const float2 v0 = mp[t * 256];
        const float2 v1 = mp[t * 256 + 64];
        const float2 v2 = mp[t * 256 + 128];
        const float2 v3 = mp[t * 256 + 192];
        a0.x += wt * v0.x; a0.y += wt * v0.y;
        a1.x += wt * v1.x; a1.y += wt * v1.y;
        a2.x += wt * v2.x; a2.y += wt * v2.y;
        a3.x += wt * v3.x; a3.y += wt * v3.y;
    }
    float2* np = (float2*)(num + ((long)b * NBLK + blk) * MD_) + lane;
    np[0] = a0; np[64] = a1; np[128] = a2; np[192] = a3;

    // --- last block of this batch combines partials (fused k_reduce) ---
    __threadfence();
    if (lane == 0) s_last = (atomicAdd(&cnt[b], 1) == NBLK - 1) ? 1 : 0;
    __syncthreads();
    if (!s_last) return;
    __threadfence();

    for (int i = lane; i < NBLK; i += 64) f_m[i] = bmax[b * NBLK + i];
    __syncthreads();
    float M = -INFINITY;
#pragma unroll 8
    for (int i = 0; i < NBLK; i++) M = fmaxf(M, f_m[i]);
    for (int i = lane; i < NBLK; i += 64)
        f_f[i] = (f_m[i] == -INFINITY) ? 0.f : expf(f_m[i] - M);
    __syncthreads();
    if (lane == 0) {
        float D = 0.f;
        for (int i = 0; i < NBLK; i++) D += f_f[i] * bden[b * NBLK + i];
        f_Ds = D;
    }
    __syncthreads();
    const float invD = 1.f / f_Ds;

    // ctx: 512 cols, 8 per lane
#pragma unroll
    for (int g = 0; g < 8; g++) {
        const int col = lane + g * 64;
        float acc = 0.f;
#pragma unroll 8
        for (int k2 = 0; k2 < NBLK; k2++)
            acc += f_f[k2] * num[((long)b * NBLK + k2) * MD_ + col];
        ctx[b * MD_ + col] = acc * invD;
    }
    // alignments: oalign holds exp(s - m_blk); rescale to softmax
    for (int t = lane; t < T_; t += 64)
        oalign[(long)b * T_ + t] *= f_f[t >> 5] * invD;
}

extern "C" void kernel_launch(void* const* d_in, const int* in_sizes, int n_in,
                              void* d_out, int out_size, void* d_ws, size_t ws_size,
                              hipStream_t stream) {
    const float* query      = (const float*)d_in[0];
    const float* memory     = (const float*)d_in[1];
    const float* alignments = (const float*)d_in[2];
    const unsigned char* mask = (const unsigned char*)d_in[3];
    const float* Wq    = (const float*)d_in[4];
    const float* bq    = (const float*)d_in[5];
    const float* Wm    = (const float*)d_in[6];
    const float* bm    = (const float*)d_in[7];
    const float* convw = (const float*)d_in[8];
    const float* convb = (const float*)d_in[9];
    const float* Wl    = (const float*)d_in[10];
    const float* bl    = (const float*)d_in[11];
    const float* vw    = (const float*)d_in[12];
    const float* vb    = (const float*)d_in[13];

    float* out = (float*)d_out;
    float* ctx = out;                      // [B,MD]
    float* oalign = out + B_ * MD_;        // [B,T]

    // workspace layout (~40.5 MB):
    //   pqp    : 8*B*AD floats    (128 KB)
    //   bmax   : B*NBLK floats    (16 KB)
    //   bden   : B*NBLK floats    (16 KB)
    //   num    : B*NBLK*MD floats (8 MB)
    //   cnt    : B ints           (128 B)
    //   wmT_sw : 65536 ushorts    (128 KB)
    //   ploc   : B*T*AD ushorts   (32 MB)
    float* ws = (float*)d_ws;
    float* pqp  = ws;
    float* bmax = pqp + 8 * B_ * AD_;
    float* bden = bmax + B_ * NBLK;
    float* num  = bden + B_ * NBLK;
    int* cnt    = (int*)(num + (long)B_ * NBLK * MD_);
    unsigned short* wmT_sw = (unsigned short*)(cnt + B_);
    unsigned short* ploc   = wmT_sw + (long)65536;

    k_pre<<<288, 256, 0, stream>>>(Wm, wmT_sw, query, Wq, pqp, cnt);
    k_ploc<<<dim3(T_ / 128, B_), 256, 0, stream>>>(alignments, convw, convb, Wl, bl, bm, bq, pqp, ploc);
    k_score_ctx<<<dim3(NBLK, B_), 64, 0, stream>>>(
        memory, mask, wmT_sw, ploc, vw, vb, bmax, bden, num, oalign, ctx, cnt);
}